// Round 9
// baseline (281.762 us; speedup 1.0000x reference)
//
#include <hip/hip_runtime.h>
#include <hip/hip_bf16.h>

typedef __hip_bfloat16 bf16;
typedef short bf16x8 __attribute__((ext_vector_type(8)));
typedef float f32x4 __attribute__((ext_vector_type(4)));
typedef unsigned int u32x4 __attribute__((ext_vector_type(4)));

// ---------- helpers ----------
__device__ __forceinline__ float b2f_us(unsigned short u) {
    union { unsigned int i; float f; } c;
    c.i = ((unsigned int)u) << 16;
    return c.f;
}
__device__ __forceinline__ unsigned short f2b_us(float f) {
    bf16 h = __float2bfloat16(f);
    return *reinterpret_cast<unsigned short*>(&h);
}
__device__ __forceinline__ void unpack8(uint4 p, float* f) {
    f[0] = b2f_us(p.x & 0xffff); f[1] = b2f_us(p.x >> 16);
    f[2] = b2f_us(p.y & 0xffff); f[3] = b2f_us(p.y >> 16);
    f[4] = b2f_us(p.z & 0xffff); f[5] = b2f_us(p.z >> 16);
    f[6] = b2f_us(p.w & 0xffff); f[7] = b2f_us(p.w >> 16);
}

// async 16B global -> LDS (global_load_lds_dwordx4)
__device__ __forceinline__ void async_copy16(const bf16* g, bf16* l) {
    __builtin_amdgcn_global_load_lds(
        (const __attribute__((address_space(1))) unsigned int*)g,
        (__attribute__((address_space(3))) unsigned int*)l, 16, 0, 0);
}

// ---------- CSR build ----------
// rank trick: atomicAdd's return value IS the within-bucket rank -> scatter needs no atomics
__global__ __launch_bounds__(256) void k_count(const int* __restrict__ col,
                                               int* __restrict__ cnt,
                                               int* __restrict__ rank, int E) {
    int e = blockIdx.x * 256 + threadIdx.x;
    if (e < E) rank[e] = atomicAdd(cnt + col[e], 1);
}
__global__ __launch_bounds__(256) void k_scan_a(const int* __restrict__ cnt,
                                                int* __restrict__ bsum,
                                                float* __restrict__ dinv) {
    __shared__ int s[256];
    int t = threadIdx.x;
    int i = blockIdx.x * 256 + t;
    int c = cnt[i];
    dinv[i] = rsqrtf((float)c + 1.0f);  // +1 self-loop
    s[t] = c;
    __syncthreads();
#pragma unroll
    for (int off = 128; off >= 1; off >>= 1) {
        if (t < off) s[t] += s[t + off];
        __syncthreads();
    }
    if (t == 0) bsum[blockIdx.x] = s[0];
}
// scan_b merged in: every block redundantly scans the 256 block sums
__global__ __launch_bounds__(256) void k_scan_c(const int* __restrict__ cnt,
                                                const int* __restrict__ bsum,
                                                int* __restrict__ rowptr) {
    __shared__ int s[256];
    __shared__ int sb[256];
    int t = threadIdx.x;
    sb[t] = bsum[t];
    __syncthreads();
#pragma unroll
    for (int off = 1; off < 256; off <<= 1) {
        int v = (t >= off) ? sb[t - off] : 0;
        __syncthreads();
        sb[t] += v;
        __syncthreads();
    }
    int boff = (blockIdx.x > 0) ? sb[blockIdx.x - 1] : 0;
    int base = blockIdx.x * 256;
    int self = cnt[base + t];
    s[t] = self;
    __syncthreads();
#pragma unroll
    for (int off = 1; off < 256; off <<= 1) {
        int v = (t >= off) ? s[t - off] : 0;
        __syncthreads();
        s[t] += v;
        __syncthreads();
    }
    rowptr[base + t] = boff + s[t] - self;  // exclusive
}

__global__ __launch_bounds__(256) void k_scatter(const int* __restrict__ row,
                                                 const int* __restrict__ col,
                                                 const float* __restrict__ dinv,
                                                 const int* __restrict__ rowptr,
                                                 const int* __restrict__ rank,
                                                 int2* __restrict__ adj, int E) {
    int e = blockIdx.x * 256 + threadIdx.x;
    if (e >= E) return;
    int r = row[e], c = col[e];
    int pos = rowptr[c] + rank[e];
    adj[pos] = make_int2(r, __float_as_int(dinv[r]));
}

// ---------- weight prep (both layers in one launch): W[K,N] f32 -> WT[N,K] bf16 ----------
__global__ __launch_bounds__(256) void k_prep_all(const float* __restrict__ W2,
                                                  bf16* __restrict__ WT2,
                                                  const float* __restrict__ W3,
                                                  bf16* __restrict__ WT3) {
    int idx = blockIdx.x * 256 + threadIdx.x;
    if (idx < 64 * 256) {
        int k = idx >> 8, n = idx & 255;           // K=64, N=256
        WT2[n * 64 + k] = __float2bfloat16(W2[idx]);
    } else {
        int i = idx - 64 * 256;
        if (i < 256 * 512) {
            int k = i >> 9, n = i & 511;           // K=256, N=512
            WT3[(size_t)n * 256 + k] = __float2bfloat16(W3[i]);
        }
    }
}

// ---------- FUSED layer 1: gather x (F=3) + 3->64 GEMM + bias + relu -> h1 ----------
// 4-way edge-split (R7 win: x is L2-resident -> latency regime; 1024 blocks, 4x chains)
__global__ __launch_bounds__(256) void k_gcn1(const int2* __restrict__ adj,
                                              const int* __restrict__ rowptr,
                                              const int* __restrict__ cnt,
                                              const float* __restrict__ dinv,
                                              const float* __restrict__ x,
                                              const float* __restrict__ W,
                                              const float* __restrict__ bias,
                                              bf16* __restrict__ h1, int N) {
    __shared__ float w[256];
    int t = threadIdx.x;
    if (t < 192) w[t] = W[t];
    else w[t] = bias[t - 192];
    __syncthreads();
    int node = blockIdx.x * 64 + (t >> 2);
    int q = t & 3;
    if (node >= N) return;
    float d = dinv[node];
    float a0 = 0.f, a1 = 0.f, a2 = 0.f;
    if (q == 0) {
        float d2 = d * d;
        a0 = x[node * 3] * d2;
        a1 = x[node * 3 + 1] * d2;
        a2 = x[node * 3 + 2] * d2;
    }
    int beg = rowptr[node], deg = cnt[node];
    int e   = beg + (deg * q) / 4;
    int end = beg + (deg * (q + 1)) / 4;
    for (; e + 3 < end; e += 4) {
        int2 ad[4];
#pragma unroll
        for (int u = 0; u < 4; ++u) ad[u] = adj[e + u];
        float xv[4][3];
#pragma unroll
        for (int u = 0; u < 4; ++u) {
            xv[u][0] = x[ad[u].x * 3];
            xv[u][1] = x[ad[u].x * 3 + 1];
            xv[u][2] = x[ad[u].x * 3 + 2];
        }
#pragma unroll
        for (int u = 0; u < 4; ++u) {
            float wt = __int_as_float(ad[u].y) * d;
            a0 += xv[u][0] * wt;
            a1 += xv[u][1] * wt;
            a2 += xv[u][2] * wt;
        }
    }
    for (; e < end; ++e) {
        int2 ad = adj[e];
        float wt = __int_as_float(ad.y) * d;
        a0 += x[ad.x * 3] * wt;
        a1 += x[ad.x * 3 + 1] * wt;
        a2 += x[ad.x * 3 + 2] * wt;
    }
    a0 += __shfl_xor(a0, 1); a1 += __shfl_xor(a1, 1); a2 += __shfl_xor(a2, 1);
    a0 += __shfl_xor(a0, 2); a1 += __shfl_xor(a1, 2); a2 += __shfl_xor(a2, 2);
    bf16* dst = h1 + (size_t)node * 64;
#pragma unroll
    for (int i = 0; i < 2; ++i) {
        int fb = q + 4 * i;
        uint4 r;
        unsigned v[4];
#pragma unroll
        for (int p = 0; p < 4; ++p) {
            int f0 = fb * 8 + p * 2;
            float u0 = fmaxf(a0 * w[f0] + a1 * w[64 + f0] + a2 * w[128 + f0] + w[192 + f0], 0.f);
            int f1 = f0 + 1;
            float u1 = fmaxf(a0 * w[f1] + a1 * w[64 + f1] + a2 * w[128 + f1] + w[192 + f1], 0.f);
            v[p] = (unsigned)f2b_us(u0) | ((unsigned)f2b_us(u1) << 16);
        }
        r.x = v[0]; r.y = v[1]; r.z = v[2]; r.w = v[3];
        *reinterpret_cast<uint4*>(dst + fb * 8) = r;
    }
}

// ========== FUSED layer 2: gather h1 (F=64) + 64->256 MFMA GEMM + bias + relu -> h2 ==========
// (R8 win: short GEMM phase -> no gather-density dilution; B panel LDS-staged once.)
__global__ __launch_bounds__(512, 4) void k_gcn2(const int2* __restrict__ adj,
                                                 const int* __restrict__ rowptr,
                                                 const int* __restrict__ cnt,
                                                 const float* __restrict__ dinv,
                                                 const bf16* __restrict__ h1,
                                                 const bf16* __restrict__ WT2,  // [256][64]
                                                 const float* __restrict__ bias,
                                                 bf16* __restrict__ h2, int N) {
    __shared__ bf16 As[64 * 64];    // 8 KB, XOR-swizzled 16B chunks
    __shared__ bf16 Bs[256 * 64];   // 32 KB, XOR-swizzled
    const int t = threadIdx.x;
    const int m0 = blockIdx.x * 64;
#pragma unroll
    for (int i = 0; i < 4; ++i) {
        int c = i * 512 + t;
        int n = c >> 3, q = c & 7;
        int qs = q ^ (n & 7);
        async_copy16(WT2 + n * 64 + qs * 8, Bs + c * 8);
    }
    {
        const int gi = t >> 4, gl = t & 15;
        const int fs = gl & 7, half = gl >> 3;
        const int fbase = fs * 8;
#pragma unroll 1
        for (int p = 0; p < 2; ++p) {
            int r = p * 32 + gi;
            int node = m0 + r;
            float d = dinv[node];
            float a[8] = {0.f, 0.f, 0.f, 0.f, 0.f, 0.f, 0.f, 0.f};
            if (half == 0) {
                uint4 sp = *reinterpret_cast<const uint4*>(h1 + (size_t)node * 64 + fbase);
                unpack8(sp, a);
                float d2 = d * d;
#pragma unroll
                for (int i = 0; i < 8; i++) a[i] *= d2;
            }
            int beg = rowptr[node], deg = cnt[node];
            int mid = beg + ((deg + 1) >> 1);
            int e = half ? mid : beg;
            int end = half ? (beg + deg) : mid;
            for (; e + 3 < end; e += 4) {
                int2 ad[4];
                uint4 pl[4];
#pragma unroll
                for (int u = 0; u < 4; ++u) ad[u] = adj[e + u];
#pragma unroll
                for (int u = 0; u < 4; ++u)
                    pl[u] = *reinterpret_cast<const uint4*>(h1 + (size_t)ad[u].x * 64 + fbase);
#pragma unroll
                for (int u = 0; u < 4; ++u) {
                    float wt = __int_as_float(ad[u].y) * d;
                    float f[8];
                    unpack8(pl[u], f);
#pragma unroll
                    for (int i = 0; i < 8; i++) a[i] += f[i] * wt;
                }
            }
            for (; e < end; ++e) {
                int2 ad = adj[e];
                float wt = __int_as_float(ad.y) * d;
                uint4 pl = *reinterpret_cast<const uint4*>(h1 + (size_t)ad.x * 64 + fbase);
                float f[8];
                unpack8(pl, f);
#pragma unroll
                for (int i = 0; i < 8; i++) a[i] += f[i] * wt;
            }
#pragma unroll
            for (int i = 0; i < 8; i++) a[i] += __shfl_xor(a[i], 8);
            if (half == 0) {
                u32x4 rr;
                rr.x = (unsigned)f2b_us(a[0]) | ((unsigned)f2b_us(a[1]) << 16);
                rr.y = (unsigned)f2b_us(a[2]) | ((unsigned)f2b_us(a[3]) << 16);
                rr.z = (unsigned)f2b_us(a[4]) | ((unsigned)f2b_us(a[5]) << 16);
                rr.w = (unsigned)f2b_us(a[6]) | ((unsigned)f2b_us(a[7]) << 16);
                int q = fs ^ (r & 7);
                *reinterpret_cast<u32x4*>(&As[r * 64 + q * 8]) = rr;
            }
        }
    }
    __syncthreads();  // drains Bs staging + As writes
    const int w = t >> 6, lane = t & 63;
    const int quad = lane >> 4, l16 = lane & 15;
    const int wmq = w & 3, wnh = w >> 2;
    f32x4 acc[8] = {};
#pragma unroll
    for (int kb = 0; kb < 2; ++kb) {
        int R = wmq * 16 + l16;
        int kc = kb * 4 + quad;
        bf16x8 af = *reinterpret_cast<const bf16x8*>(&As[R * 64 + (kc ^ (R & 7)) * 8]);
#pragma unroll
        for (int j = 0; j < 8; ++j) {
            int n = wnh * 128 + j * 16 + l16;
            bf16x8 bfr = *reinterpret_cast<const bf16x8*>(&Bs[n * 64 + (kc ^ (n & 7)) * 8]);
            acc[j] = __builtin_amdgcn_mfma_f32_16x16x32_bf16(af, bfr, acc[j], 0, 0, 0);
        }
    }
#pragma unroll
    for (int j = 0; j < 8; ++j) {
        int cn = wnh * 128 + j * 16 + l16;
        float bv = bias[cn];
#pragma unroll
        for (int r = 0; r < 4; ++r) {
            int row = m0 + wmq * 16 + quad * 4 + r;
            h2[(size_t)row * 256 + cn] = __float2bfloat16(fmaxf(acc[j][r] + bv, 0.f));
        }
    }
}

// ---------- CSR gather (bf16 -> bf16, incl. self; 8 feats/lane) ----------
// EDGE-SPLIT x2. MUST stay standalone & dense for layer 3 (R3 dilution lesson);
// pattern ceiling ~3.7 TB/s regardless of occupancy (R0 vs R2).
template <int F>
__global__ __launch_bounds__(256, 8) void k_gather_pre(const int2* __restrict__ adj,
                                                       const int* __restrict__ rowptr,
                                                       const int* __restrict__ cnt,
                                                       const float* __restrict__ dinv,
                                                       const bf16* __restrict__ h,
                                                       bf16* __restrict__ agg, int N) {
    constexpr int LPN = F / 8;
    constexpr int GRP = 2 * LPN;
    constexpr int NPB = 256 / GRP;
    int t = threadIdx.x;
    int node = blockIdx.x * NPB + t / GRP;
    if (node >= N) return;
    int gl = t % GRP;
    int fs = gl % LPN;
    int half = gl / LPN;
    int fbase = fs * 8;
    float d = dinv[node];
    size_t sbase = (size_t)node * F + fbase;
    float a[8] = {0.f, 0.f, 0.f, 0.f, 0.f, 0.f, 0.f, 0.f};
    if (half == 0) {
        uint4 sp = *reinterpret_cast<const uint4*>(h + sbase);
        unpack8(sp, a);
        float d2 = d * d;
#pragma unroll
        for (int i = 0; i < 8; i++) a[i] *= d2;
    }
    int beg = rowptr[node];
    int deg = cnt[node];
    int mid = beg + ((deg + 1) >> 1);
    int e   = half ? mid : beg;
    int end = half ? (beg + deg) : mid;
    for (; e + 3 < end; e += 4) {
        int2 ad[4];
        uint4 p[4];
#pragma unroll
        for (int u = 0; u < 4; ++u) ad[u] = adj[e + u];
#pragma unroll
        for (int u = 0; u < 4; ++u)
            p[u] = *reinterpret_cast<const uint4*>(h + (size_t)ad[u].x * F + fbase);
#pragma unroll
        for (int u = 0; u < 4; ++u) {
            float wt = __int_as_float(ad[u].y) * d;
            float f[8];
            unpack8(p[u], f);
#pragma unroll
            for (int i = 0; i < 8; i++) a[i] += f[i] * wt;
        }
    }
    for (; e < end; ++e) {
        int2 ad = adj[e];
        float wt = __int_as_float(ad.y) * d;
        uint4 p = *reinterpret_cast<const uint4*>(h + (size_t)ad.x * F + fbase);
        float f[8];
        unpack8(p, f);
#pragma unroll
        for (int i = 0; i < 8; i++) a[i] += f[i] * wt;
    }
#pragma unroll
    for (int i = 0; i < 8; i++) a[i] += __shfl_xor(a[i], LPN);
    if (half == 0) {
        u32x4 r;
        r.x = (unsigned)f2b_us(a[0]) | ((unsigned)f2b_us(a[1]) << 16);
        r.y = (unsigned)f2b_us(a[2]) | ((unsigned)f2b_us(a[3]) << 16);
        r.z = (unsigned)f2b_us(a[4]) | ((unsigned)f2b_us(a[5]) << 16);
        r.w = (unsigned)f2b_us(a[6]) | ((unsigned)f2b_us(a[7]) << 16);
        __builtin_nontemporal_store(r, reinterpret_cast<u32x4*>(agg + sbase));
    }
}

// ---------- MFMA GEMM + bias + relu + per-block pool partials ----------
// 256x256 tile (8 waves, 2x4), BK=32: halves LDS-staging traffic vs 128x128 and
// doubles MFMA-per-barrier, keeping the PROVEN fragment/staging pattern (R0/R2).
// partials layout: [mt*2+wm][ sum(512) | max(512) ]; block(nt) writes cols nt*256..
__global__ __launch_bounds__(512) void k_gemm_pool(const bf16* __restrict__ A,
                                                   const bf16* __restrict__ BT,
                                                   const float* __restrict__ bias,
                                                   float* __restrict__ partials,
                                                   int M, int N, int K) {
    __shared__ bf16 As[256 * 32];  // 16 KB
    __shared__ bf16 Bs[256 * 32];  // 16 KB
    const int t = threadIdx.x;
    const int wave = t >> 6, lane = t & 63;
    const int quad = lane >> 4, l16 = lane & 15;
    const int wm = wave & 1, wn = wave >> 1;   // wm: m-half(128), wn: n-quarter(64)
    const int mt = blockIdx.x >> 1, nt = blockIdx.x & 1;
    const int m0 = mt * 256, n0 = nt * 256;

    f32x4 acc[8][4] = {};
    for (int kb = 0; kb < K; kb += 32) {
#pragma unroll
        for (int rnd = 0; rnd < 2; ++rnd) {
            int c = rnd * 512 + t;         // chunk 0..1023; 16B each; wave-linear
            int r = c >> 2, seg = c & 3;
            async_copy16(A + (size_t)(m0 + r) * K + kb + seg * 8, As + c * 8);
            async_copy16(BT + (size_t)(n0 + r) * K + kb + seg * 8, Bs + c * 8);
        }
        __syncthreads();
        bf16x8 af[8], bfr[4];
#pragma unroll
        for (int i = 0; i < 8; i++)
            af[i] = *reinterpret_cast<const bf16x8*>(&As[(wm * 128 + i * 16 + l16) * 32 + quad * 8]);
#pragma unroll
        for (int j = 0; j < 4; j++)
            bfr[j] = *reinterpret_cast<const bf16x8*>(&Bs[(wn * 64 + j * 16 + l16) * 32 + quad * 8]);
#pragma unroll
        for (int i = 0; i < 8; i++)
#pragma unroll
            for (int j = 0; j < 4; j++)
                acc[i][j] = __builtin_amdgcn_mfma_f32_16x16x32_bf16(af[i], bfr[j], acc[i][j], 0, 0, 0);
        __syncthreads();
    }
    size_t pbase = (size_t)(mt * 2 + wm) * 1024;
#pragma unroll
    for (int j = 0; j < 4; j++) {
        int f = wn * 64 + j * 16 + l16;      // within 256-col block
        float bv = bias[n0 + f];
        float s = 0.f, mx = 0.f;
#pragma unroll
        for (int i = 0; i < 8; i++)
#pragma unroll
            for (int r = 0; r < 4; r++) {
                float v = fmaxf(acc[i][j][r] + bv, 0.f);
                s += v;
                mx = fmaxf(mx, v);
            }
        s += __shfl_xor(s, 16);
        s += __shfl_xor(s, 32);
        mx = fmaxf(mx, __shfl_xor(mx, 16));
        mx = fmaxf(mx, __shfl_xor(mx, 32));
        if (quad == 0) {
            partials[pbase + n0 + f] = s;
            partials[pbase + 512 + n0 + f] = mx;
        }
    }
}

// ---------- fused MLP head: pool-final + mlp1 + relu + mlp2; one block per graph ----------
__global__ __launch_bounds__(256) void k_mlp(const float* __restrict__ partials,
                                             const float* __restrict__ Wm1,
                                             const float* __restrict__ bm1,
                                             const float* __restrict__ Wm2,
                                             const float* __restrict__ bm2,
                                             float* __restrict__ out) {
    __shared__ float hg[1024];
    __shared__ float m2[512];
    int g = blockIdx.x;
    int t = threadIdx.x;
    // pool: graph g spans m-tiles g*4..g*4+4 -> (mt*2+wm) indices g*8..g*8+8
    for (int ff = t; ff < 512; ff += 256) {
        float S = 0.f, M = 0.f;
#pragma unroll
        for (int k = 0; k < 8; ++k) {
            size_t pbase = (size_t)(g * 8 + k) * 1024;
            S += partials[pbase + ff];
            M = fmaxf(M, partials[pbase + 512 + ff]);
        }
        hg[ff] = S * (1.0f / 1024.0f);
        hg[512 + ff] = M;
    }
    __syncthreads();
    // mlp1: each thread computes 2 outputs (f = t, t+256), K=1024, 4 accumulators
#pragma unroll 1
    for (int fo = 0; fo < 2; ++fo) {
        int f = fo * 256 + t;
        float a0 = 0.f, a1 = 0.f, a2 = 0.f, a3 = 0.f;
        for (int k = 0; k < 1024; k += 4) {
            a0 += hg[k]     * Wm1[(size_t)k * 512 + f];
            a1 += hg[k + 1] * Wm1[(size_t)(k + 1) * 512 + f];
            a2 += hg[k + 2] * Wm1[(size_t)(k + 2) * 512 + f];
            a3 += hg[k + 3] * Wm1[(size_t)(k + 3) * 512 + f];
        }
        m2[f] = fmaxf(a0 + a1 + a2 + a3 + bm1[f], 0.f);
    }
    __syncthreads();
    // mlp2: 16 lanes per output, 10 outputs
    int j = t >> 4, l = t & 15;
    float acc = 0.f;
    if (j < 10) {
        int k0 = l * 32;
#pragma unroll
        for (int i = 0; i < 32; ++i)
            acc += m2[k0 + i] * Wm2[(size_t)(k0 + i) * 10 + j];
    }
#pragma unroll
    for (int m = 8; m >= 1; m >>= 1) acc += __shfl_xor(acc, m);
    if (j < 10 && l == 0) out[g * 10 + j] = acc + bm2[j];
}

extern "C" void kernel_launch(void* const* d_in, const int* in_sizes, int n_in,
                              void* d_out, int out_size, void* d_ws, size_t ws_size,
                              hipStream_t stream) {
    const float* x   = (const float*)d_in[0];
    const int*   ei  = (const int*)d_in[1];
    const float* W1  = (const float*)d_in[3];
    const float* b1  = (const float*)d_in[4];
    const float* W2  = (const float*)d_in[5];
    const float* b2  = (const float*)d_in[6];
    const float* W3  = (const float*)d_in[7];
    const float* b3  = (const float*)d_in[8];
    const float* Wm1 = (const float*)d_in[9];
    const float* bm1 = (const float*)d_in[10];
    const float* Wm2 = (const float*)d_in[11];
    const float* bm2 = (const float*)d_in[12];
    float* out = (float*)d_out;

    const int N = in_sizes[0] / 3;  // 65536
    const int E = in_sizes[1] / 2;  // 524288
    const int* row = ei;
    const int* col = ei + E;

    char* ws = (char*)d_ws;
    size_t off = 0;
    auto alloc = [&](size_t bytes) {
        void* p = ws + off;
        off += (bytes + 255) & ~(size_t)255;
        return p;
    };
    int*   cnt      = (int*)alloc((size_t)N * 4);
    int*   rowptr   = (int*)alloc((size_t)N * 4);
    float* dinv     = (float*)alloc((size_t)N * 4);
    int*   bsum     = (int*)alloc(256 * 4);
    int*   rank     = (int*)alloc((size_t)E * 4);
    int2*  adj      = (int2*)alloc((size_t)E * 8);
    bf16*  h1       = (bf16*)alloc((size_t)N * 64 * 2);
    bf16*  h2       = (bf16*)alloc((size_t)N * 256 * 2);
    bf16*  agg3     = (bf16*)alloc((size_t)N * 256 * 2);
    bf16*  WT2      = (bf16*)alloc(256 * 64 * 2);
    bf16*  WT3      = (bf16*)alloc(512 * 256 * 2);
    float* partials = (float*)alloc((size_t)512 * 1024 * 4);  // 2 MB
    float* m1       = (float*)alloc(64 * 512 * 4);
    (void)m1;

    // ---- CSR build (once; reused by all 3 layers) ----
    (void)hipMemsetAsync(cnt, 0, (size_t)N * 4, stream);
    k_count<<<(E + 255) / 256, 256, 0, stream>>>(col, cnt, rank, E);
    k_scan_a<<<256, 256, 0, stream>>>(cnt, bsum, dinv);
    k_scan_c<<<256, 256, 0, stream>>>(cnt, bsum, rowptr);
    k_scatter<<<(E + 255) / 256, 256, 0, stream>>>(row, col, dinv, rowptr, rank, adj, E);

    // ---- weight prep (single launch) ----
    k_prep_all<<<(64 * 256 + 256 * 512 + 255) / 256, 256, 0, stream>>>(W2, WT2, W3, WT3);

    // ---- layer 1: fused gather(F=3) + 3->64 GEMM + bias + relu (4-way edge-split) ----
    k_gcn1<<<N / 64, 256, 0, stream>>>(adj, rowptr, cnt, dinv, x, W1, b1, h1, N);

    // ---- layer 2: FUSED gather(F=64) + 64->256 MFMA GEMM + bias + relu ----
    k_gcn2<<<N / 64, 512, 0, stream>>>(adj, rowptr, cnt, dinv, h1, WT2, b2, h2, N);

    // ---- layer 3: gather h2 (F=256), then 256x256-tile MFMA GEMM + pool partials ----
    k_gather_pre<256><<<(N * 64) / 256, 256, 0, stream>>>(adj, rowptr, cnt, dinv, h2, agg3, N);
    k_gemm_pool<<<(N / 256) * 2, 512, 0, stream>>>(agg3, WT3, b3, partials, N, 512, 256);

    // ---- fused MLP head ----
    k_mlp<<<64, 256, 0, stream>>>(partials, Wm1, bm1, Wm2, bm2, out);
}

// Round 11
// 242.611 us; speedup vs baseline: 1.1614x; 1.1614x over previous
//
#include <hip/hip_runtime.h>
#include <hip/hip_bf16.h>

typedef __hip_bfloat16 bf16;
typedef short bf16x8 __attribute__((ext_vector_type(8)));
typedef float f32x4 __attribute__((ext_vector_type(4)));
typedef unsigned int u32x4 __attribute__((ext_vector_type(4)));

// ---------- helpers ----------
__device__ __forceinline__ float b2f_us(unsigned short u) {
    union { unsigned int i; float f; } c;
    c.i = ((unsigned int)u) << 16;
    return c.f;
}
__device__ __forceinline__ unsigned short f2b_us(float f) {
    bf16 h = __float2bfloat16(f);
    return *reinterpret_cast<unsigned short*>(&h);
}
__device__ __forceinline__ void unpack8(uint4 p, float* f) {
    f[0] = b2f_us(p.x & 0xffff); f[1] = b2f_us(p.x >> 16);
    f[2] = b2f_us(p.y & 0xffff); f[3] = b2f_us(p.y >> 16);
    f[4] = b2f_us(p.z & 0xffff); f[5] = b2f_us(p.z >> 16);
    f[6] = b2f_us(p.w & 0xffff); f[7] = b2f_us(p.w >> 16);
}

// async 16B global -> LDS (global_load_lds_dwordx4)
__device__ __forceinline__ void async_copy16(const bf16* g, bf16* l) {
    __builtin_amdgcn_global_load_lds(
        (const __attribute__((address_space(1))) unsigned int*)g,
        (__attribute__((address_space(3))) unsigned int*)l, 16, 0, 0);
}

// ---------- CSR build ----------
// rank trick: atomicAdd's return value IS the within-bucket rank -> scatter needs no atomics
__global__ __launch_bounds__(256) void k_count(const int* __restrict__ col,
                                               int* __restrict__ cnt,
                                               int* __restrict__ rank, int E) {
    int e = blockIdx.x * 256 + threadIdx.x;
    if (e < E) rank[e] = atomicAdd(cnt + col[e], 1);
}
__global__ __launch_bounds__(256) void k_scan_a(const int* __restrict__ cnt,
                                                int* __restrict__ bsum,
                                                float* __restrict__ dinv) {
    __shared__ int s[256];
    int t = threadIdx.x;
    int i = blockIdx.x * 256 + t;
    int c = cnt[i];
    dinv[i] = rsqrtf((float)c + 1.0f);  // +1 self-loop
    s[t] = c;
    __syncthreads();
#pragma unroll
    for (int off = 128; off >= 1; off >>= 1) {
        if (t < off) s[t] += s[t + off];
        __syncthreads();
    }
    if (t == 0) bsum[blockIdx.x] = s[0];
}
// scan_b merged in: every block redundantly scans the 256 block sums
__global__ __launch_bounds__(256) void k_scan_c(const int* __restrict__ cnt,
                                                const int* __restrict__ bsum,
                                                int* __restrict__ rowptr) {
    __shared__ int s[256];
    __shared__ int sb[256];
    int t = threadIdx.x;
    sb[t] = bsum[t];
    __syncthreads();
#pragma unroll
    for (int off = 1; off < 256; off <<= 1) {
        int v = (t >= off) ? sb[t - off] : 0;
        __syncthreads();
        sb[t] += v;
        __syncthreads();
    }
    int boff = (blockIdx.x > 0) ? sb[blockIdx.x - 1] : 0;
    int base = blockIdx.x * 256;
    int self = cnt[base + t];
    s[t] = self;
    __syncthreads();
#pragma unroll
    for (int off = 1; off < 256; off <<= 1) {
        int v = (t >= off) ? s[t - off] : 0;
        __syncthreads();
        s[t] += v;
        __syncthreads();
    }
    rowptr[base + t] = boff + s[t] - self;  // exclusive
}

__global__ __launch_bounds__(256) void k_scatter(const int* __restrict__ row,
                                                 const int* __restrict__ col,
                                                 const float* __restrict__ dinv,
                                                 const int* __restrict__ rowptr,
                                                 const int* __restrict__ rank,
                                                 int2* __restrict__ adj, int E) {
    int e = blockIdx.x * 256 + threadIdx.x;
    if (e >= E) return;
    int r = row[e], c = col[e];
    int pos = rowptr[c] + rank[e];
    adj[pos] = make_int2(r, __float_as_int(dinv[r]));
}

// ---------- weight prep (both layers in one launch): W[K,N] f32 -> WT[N,K] bf16 ----------
__global__ __launch_bounds__(256) void k_prep_all(const float* __restrict__ W2,
                                                  bf16* __restrict__ WT2,
                                                  const float* __restrict__ W3,
                                                  bf16* __restrict__ WT3) {
    int idx = blockIdx.x * 256 + threadIdx.x;
    if (idx < 64 * 256) {
        int k = idx >> 8, n = idx & 255;           // K=64, N=256
        WT2[n * 64 + k] = __float2bfloat16(W2[idx]);
    } else {
        int i = idx - 64 * 256;
        if (i < 256 * 512) {
            int k = i >> 9, n = i & 511;           // K=256, N=512
            WT3[(size_t)n * 256 + k] = __float2bfloat16(W3[i]);
        }
    }
}

// ---------- FUSED layer 1: gather x (F=3) + 3->64 GEMM + bias + relu -> h1 ----------
// 4-way edge-split (R7 win: x is L2-resident -> latency regime; 1024 blocks, 4x chains)
__global__ __launch_bounds__(256) void k_gcn1(const int2* __restrict__ adj,
                                              const int* __restrict__ rowptr,
                                              const int* __restrict__ cnt,
                                              const float* __restrict__ dinv,
                                              const float* __restrict__ x,
                                              const float* __restrict__ W,
                                              const float* __restrict__ bias,
                                              bf16* __restrict__ h1, int N) {
    __shared__ float w[256];
    int t = threadIdx.x;
    if (t < 192) w[t] = W[t];
    else w[t] = bias[t - 192];
    __syncthreads();
    int node = blockIdx.x * 64 + (t >> 2);
    int q = t & 3;
    if (node >= N) return;
    float d = dinv[node];
    float a0 = 0.f, a1 = 0.f, a2 = 0.f;
    if (q == 0) {
        float d2 = d * d;
        a0 = x[node * 3] * d2;
        a1 = x[node * 3 + 1] * d2;
        a2 = x[node * 3 + 2] * d2;
    }
    int beg = rowptr[node], deg = cnt[node];
    int e   = beg + (deg * q) / 4;
    int end = beg + (deg * (q + 1)) / 4;
    for (; e + 3 < end; e += 4) {
        int2 ad[4];
#pragma unroll
        for (int u = 0; u < 4; ++u) ad[u] = adj[e + u];
        float xv[4][3];
#pragma unroll
        for (int u = 0; u < 4; ++u) {
            xv[u][0] = x[ad[u].x * 3];
            xv[u][1] = x[ad[u].x * 3 + 1];
            xv[u][2] = x[ad[u].x * 3 + 2];
        }
#pragma unroll
        for (int u = 0; u < 4; ++u) {
            float wt = __int_as_float(ad[u].y) * d;
            a0 += xv[u][0] * wt;
            a1 += xv[u][1] * wt;
            a2 += xv[u][2] * wt;
        }
    }
    for (; e < end; ++e) {
        int2 ad = adj[e];
        float wt = __int_as_float(ad.y) * d;
        a0 += x[ad.x * 3] * wt;
        a1 += x[ad.x * 3 + 1] * wt;
        a2 += x[ad.x * 3 + 2] * wt;
    }
    a0 += __shfl_xor(a0, 1); a1 += __shfl_xor(a1, 1); a2 += __shfl_xor(a2, 1);
    a0 += __shfl_xor(a0, 2); a1 += __shfl_xor(a1, 2); a2 += __shfl_xor(a2, 2);
    bf16* dst = h1 + (size_t)node * 64;
#pragma unroll
    for (int i = 0; i < 2; ++i) {
        int fb = q + 4 * i;
        uint4 r;
        unsigned v[4];
#pragma unroll
        for (int p = 0; p < 4; ++p) {
            int f0 = fb * 8 + p * 2;
            float u0 = fmaxf(a0 * w[f0] + a1 * w[64 + f0] + a2 * w[128 + f0] + w[192 + f0], 0.f);
            int f1 = f0 + 1;
            float u1 = fmaxf(a0 * w[f1] + a1 * w[64 + f1] + a2 * w[128 + f1] + w[192 + f1], 0.f);
            v[p] = (unsigned)f2b_us(u0) | ((unsigned)f2b_us(u1) << 16);
        }
        r.x = v[0]; r.y = v[1]; r.z = v[2]; r.w = v[3];
        *reinterpret_cast<uint4*>(dst + fb * 8) = r;
    }
}

// ========== FUSED layer 2: gather h1 (F=64) + 64->256 MFMA GEMM + bias + relu -> h2 ==========
// (R8 win: short GEMM phase -> no gather-density dilution; B panel LDS-staged once.)
__global__ __launch_bounds__(512, 4) void k_gcn2(const int2* __restrict__ adj,
                                                 const int* __restrict__ rowptr,
                                                 const int* __restrict__ cnt,
                                                 const float* __restrict__ dinv,
                                                 const bf16* __restrict__ h1,
                                                 const bf16* __restrict__ WT2,  // [256][64]
                                                 const float* __restrict__ bias,
                                                 bf16* __restrict__ h2, int N) {
    __shared__ bf16 As[64 * 64];    // 8 KB, XOR-swizzled 16B chunks
    __shared__ bf16 Bs[256 * 64];   // 32 KB, XOR-swizzled
    const int t = threadIdx.x;
    const int m0 = blockIdx.x * 64;
#pragma unroll
    for (int i = 0; i < 4; ++i) {
        int c = i * 512 + t;
        int n = c >> 3, q = c & 7;
        int qs = q ^ (n & 7);
        async_copy16(WT2 + n * 64 + qs * 8, Bs + c * 8);
    }
    {
        const int gi = t >> 4, gl = t & 15;
        const int fs = gl & 7, half = gl >> 3;
        const int fbase = fs * 8;
#pragma unroll 1
        for (int p = 0; p < 2; ++p) {
            int r = p * 32 + gi;
            int node = m0 + r;
            float d = dinv[node];
            float a[8] = {0.f, 0.f, 0.f, 0.f, 0.f, 0.f, 0.f, 0.f};
            if (half == 0) {
                uint4 sp = *reinterpret_cast<const uint4*>(h1 + (size_t)node * 64 + fbase);
                unpack8(sp, a);
                float d2 = d * d;
#pragma unroll
                for (int i = 0; i < 8; i++) a[i] *= d2;
            }
            int beg = rowptr[node], deg = cnt[node];
            int mid = beg + ((deg + 1) >> 1);
            int e = half ? mid : beg;
            int end = half ? (beg + deg) : mid;
            for (; e + 3 < end; e += 4) {
                int2 ad[4];
                uint4 pl[4];
#pragma unroll
                for (int u = 0; u < 4; ++u) ad[u] = adj[e + u];
#pragma unroll
                for (int u = 0; u < 4; ++u)
                    pl[u] = *reinterpret_cast<const uint4*>(h1 + (size_t)ad[u].x * 64 + fbase);
#pragma unroll
                for (int u = 0; u < 4; ++u) {
                    float wt = __int_as_float(ad[u].y) * d;
                    float f[8];
                    unpack8(pl[u], f);
#pragma unroll
                    for (int i = 0; i < 8; i++) a[i] += f[i] * wt;
                }
            }
            for (; e < end; ++e) {
                int2 ad = adj[e];
                float wt = __int_as_float(ad.y) * d;
                uint4 pl = *reinterpret_cast<const uint4*>(h1 + (size_t)ad.x * 64 + fbase);
                float f[8];
                unpack8(pl, f);
#pragma unroll
                for (int i = 0; i < 8; i++) a[i] += f[i] * wt;
            }
#pragma unroll
            for (int i = 0; i < 8; i++) a[i] += __shfl_xor(a[i], 8);
            if (half == 0) {
                u32x4 rr;
                rr.x = (unsigned)f2b_us(a[0]) | ((unsigned)f2b_us(a[1]) << 16);
                rr.y = (unsigned)f2b_us(a[2]) | ((unsigned)f2b_us(a[3]) << 16);
                rr.z = (unsigned)f2b_us(a[4]) | ((unsigned)f2b_us(a[5]) << 16);
                rr.w = (unsigned)f2b_us(a[6]) | ((unsigned)f2b_us(a[7]) << 16);
                int q = fs ^ (r & 7);
                *reinterpret_cast<u32x4*>(&As[r * 64 + q * 8]) = rr;
            }
        }
    }
    __syncthreads();  // drains Bs staging + As writes
    const int w = t >> 6, lane = t & 63;
    const int quad = lane >> 4, l16 = lane & 15;
    const int wmq = w & 3, wnh = w >> 2;
    f32x4 acc[8] = {};
#pragma unroll
    for (int kb = 0; kb < 2; ++kb) {
        int R = wmq * 16 + l16;
        int kc = kb * 4 + quad;
        bf16x8 af = *reinterpret_cast<const bf16x8*>(&As[R * 64 + (kc ^ (R & 7)) * 8]);
#pragma unroll
        for (int j = 0; j < 8; ++j) {
            int n = wnh * 128 + j * 16 + l16;
            bf16x8 bfr = *reinterpret_cast<const bf16x8*>(&Bs[n * 64 + (kc ^ (n & 7)) * 8]);
            acc[j] = __builtin_amdgcn_mfma_f32_16x16x32_bf16(af, bfr, acc[j], 0, 0, 0);
        }
    }
#pragma unroll
    for (int j = 0; j < 8; ++j) {
        int cn = wnh * 128 + j * 16 + l16;
        float bv = bias[cn];
#pragma unroll
        for (int r = 0; r < 4; ++r) {
            int row = m0 + wmq * 16 + quad * 4 + r;
            h2[(size_t)row * 256 + cn] = __float2bfloat16(fmaxf(acc[j][r] + bv, 0.f));
        }
    }
}

// ---------- CSR gather (bf16 -> bf16, incl. self; 8 feats/lane) ----------
// EDGE-SPLIT x2. MUST stay standalone & dense for layer 3 (R3 dilution lesson);
// pattern ceiling ~3.7 TB/s regardless of occupancy (R0 vs R2).
template <int F>
__global__ __launch_bounds__(256, 8) void k_gather_pre(const int2* __restrict__ adj,
                                                       const int* __restrict__ rowptr,
                                                       const int* __restrict__ cnt,
                                                       const float* __restrict__ dinv,
                                                       const bf16* __restrict__ h,
                                                       bf16* __restrict__ agg, int N) {
    constexpr int LPN = F / 8;
    constexpr int GRP = 2 * LPN;
    constexpr int NPB = 256 / GRP;
    int t = threadIdx.x;
    int node = blockIdx.x * NPB + t / GRP;
    if (node >= N) return;
    int gl = t % GRP;
    int fs = gl % LPN;
    int half = gl / LPN;
    int fbase = fs * 8;
    float d = dinv[node];
    size_t sbase = (size_t)node * F + fbase;
    float a[8] = {0.f, 0.f, 0.f, 0.f, 0.f, 0.f, 0.f, 0.f};
    if (half == 0) {
        uint4 sp = *reinterpret_cast<const uint4*>(h + sbase);
        unpack8(sp, a);
        float d2 = d * d;
#pragma unroll
        for (int i = 0; i < 8; i++) a[i] *= d2;
    }
    int beg = rowptr[node];
    int deg = cnt[node];
    int mid = beg + ((deg + 1) >> 1);
    int e   = half ? mid : beg;
    int end = half ? (beg + deg) : mid;
    for (; e + 3 < end; e += 4) {
        int2 ad[4];
        uint4 p[4];
#pragma unroll
        for (int u = 0; u < 4; ++u) ad[u] = adj[e + u];
#pragma unroll
        for (int u = 0; u < 4; ++u)
            p[u] = *reinterpret_cast<const uint4*>(h + (size_t)ad[u].x * F + fbase);
#pragma unroll
        for (int u = 0; u < 4; ++u) {
            float wt = __int_as_float(ad[u].y) * d;
            float f[8];
            unpack8(p[u], f);
#pragma unroll
            for (int i = 0; i < 8; i++) a[i] += f[i] * wt;
        }
    }
    for (; e < end; ++e) {
        int2 ad = adj[e];
        float wt = __int_as_float(ad.y) * d;
        uint4 p = *reinterpret_cast<const uint4*>(h + (size_t)ad.x * F + fbase);
        float f[8];
        unpack8(p, f);
#pragma unroll
        for (int i = 0; i < 8; i++) a[i] += f[i] * wt;
    }
#pragma unroll
    for (int i = 0; i < 8; i++) a[i] += __shfl_xor(a[i], LPN);
    if (half == 0) {
        u32x4 r;
        r.x = (unsigned)f2b_us(a[0]) | ((unsigned)f2b_us(a[1]) << 16);
        r.y = (unsigned)f2b_us(a[2]) | ((unsigned)f2b_us(a[3]) << 16);
        r.z = (unsigned)f2b_us(a[4]) | ((unsigned)f2b_us(a[5]) << 16);
        r.w = (unsigned)f2b_us(a[6]) | ((unsigned)f2b_us(a[7]) << 16);
        __builtin_nontemporal_store(r, reinterpret_cast<u32x4*>(agg + sbase));
    }
}

// ---------- MFMA GEMM + bias + relu + per-block pool partials ----------
// 256x256 tile (8 waves, 2x4), BK=32 (R9 win: ~25us faster than 128x128 - halves
// staged bytes, doubles MFMA-per-barrier, keeps proven fragment pattern).
// partials layout: [mt*2+wm][ sum(512) | max(512) ]; block(nt) writes cols nt*256..
__global__ __launch_bounds__(512) void k_gemm_pool(const bf16* __restrict__ A,
                                                   const bf16* __restrict__ BT,
                                                   const float* __restrict__ bias,
                                                   float* __restrict__ partials,
                                                   int M, int N, int K) {
    __shared__ bf16 As[256 * 32];  // 16 KB
    __shared__ bf16 Bs[256 * 32];  // 16 KB
    const int t = threadIdx.x;
    const int wave = t >> 6, lane = t & 63;
    const int quad = lane >> 4, l16 = lane & 15;
    const int wm = wave & 1, wn = wave >> 1;   // wm: m-half(128), wn: n-quarter(64)
    const int mt = blockIdx.x >> 1, nt = blockIdx.x & 1;
    const int m0 = mt * 256, n0 = nt * 256;

    f32x4 acc[8][4] = {};
    for (int kb = 0; kb < K; kb += 32) {
#pragma unroll
        for (int rnd = 0; rnd < 2; ++rnd) {
            int c = rnd * 512 + t;         // chunk 0..1023; 16B each; wave-linear
            int r = c >> 2, seg = c & 3;
            async_copy16(A + (size_t)(m0 + r) * K + kb + seg * 8, As + c * 8);
            async_copy16(BT + (size_t)(n0 + r) * K + kb + seg * 8, Bs + c * 8);
        }
        __syncthreads();
        bf16x8 af[8], bfr[4];
#pragma unroll
        for (int i = 0; i < 8; i++)
            af[i] = *reinterpret_cast<const bf16x8*>(&As[(wm * 128 + i * 16 + l16) * 32 + quad * 8]);
#pragma unroll
        for (int j = 0; j < 4; j++)
            bfr[j] = *reinterpret_cast<const bf16x8*>(&Bs[(wn * 64 + j * 16 + l16) * 32 + quad * 8]);
#pragma unroll
        for (int i = 0; i < 8; i++)
#pragma unroll
            for (int j = 0; j < 4; j++)
                acc[i][j] = __builtin_amdgcn_mfma_f32_16x16x32_bf16(af[i], bfr[j], acc[i][j], 0, 0, 0);
        __syncthreads();
    }
    size_t pbase = (size_t)(mt * 2 + wm) * 1024;
#pragma unroll
    for (int j = 0; j < 4; j++) {
        int f = wn * 64 + j * 16 + l16;      // within 256-col block
        float bv = bias[n0 + f];
        float s = 0.f, mx = 0.f;
#pragma unroll
        for (int i = 0; i < 8; i++)
#pragma unroll
            for (int r = 0; r < 4; r++) {
                float v = fmaxf(acc[i][j][r] + bv, 0.f);
                s += v;
                mx = fmaxf(mx, v);
            }
        s += __shfl_xor(s, 16);
        s += __shfl_xor(s, 32);
        mx = fmaxf(mx, __shfl_xor(mx, 16));
        mx = fmaxf(mx, __shfl_xor(mx, 32));
        if (quad == 0) {
            partials[pbase + n0 + f] = s;
            partials[pbase + 512 + n0 + f] = mx;
        }
    }
}

// ---------- MLP layer 1 + pool-final (PROVEN R8 shape: 512 blocks, high occupancy).
// R9 lesson: single-block-per-graph fused MLP = 2.7% occupancy, 70us. Keep 64x8 grid.
__global__ __launch_bounds__(256) void k_mlp1(const float* __restrict__ partials,
                                              const float* __restrict__ Wm1,
                                              const float* __restrict__ bm1,
                                              float* __restrict__ o) {
    __shared__ float hg[1024];
    __shared__ float red[256];
    int g = blockIdx.x;
    int t = threadIdx.x;
    // pool: graph g spans (mt*2+wm) indices g*8..g*8+8; layout [k][sum512|max512]
    for (int ff = t; ff < 512; ff += 256) {
        float S = 0.f, M = 0.f;
#pragma unroll
        for (int k = 0; k < 8; ++k) {
            size_t pbase = (size_t)(g * 8 + k) * 1024;
            S += partials[pbase + ff];
            M = fmaxf(M, partials[pbase + 512 + ff]);
        }
        hg[ff] = S * (1.0f / 1024.0f);
        hg[512 + ff] = M;
    }
    __syncthreads();
    int f64 = t & 63, kq = t >> 6;
    int f = blockIdx.y * 64 + f64;
    float acc = 0.f;
    int k0 = kq * 256;
#pragma unroll 8
    for (int k = k0; k < k0 + 256; ++k)
        acc += hg[k] * Wm1[(size_t)k * 512 + f];
    red[t] = acc;
    __syncthreads();
    if (t < 64) {
        float total = red[t] + red[t + 64] + red[t + 128] + red[t + 192] + bm1[f];
        o[g * 512 + f] = fmaxf(total, 0.f);
    }
}

__global__ __launch_bounds__(512) void k_mlp2(const float* __restrict__ h,
                                              const float* __restrict__ Wm2,
                                              const float* __restrict__ bm2,
                                              float* __restrict__ out) {
    int g = blockIdx.x;
    int t = threadIdx.x;
    int j = t >> 5, lane32 = t & 31;
    float acc = 0.f;
    if (j < 10) {
        int k0 = lane32 * 16;
#pragma unroll
        for (int i = 0; i < 16; ++i)
            acc += h[g * 512 + k0 + i] * Wm2[(size_t)(k0 + i) * 10 + j];
    }
#pragma unroll
    for (int m = 16; m >= 1; m >>= 1) acc += __shfl_xor(acc, m);
    if (j < 10 && lane32 == 0) out[g * 10 + j] = acc + bm2[j];
}

extern "C" void kernel_launch(void* const* d_in, const int* in_sizes, int n_in,
                              void* d_out, int out_size, void* d_ws, size_t ws_size,
                              hipStream_t stream) {
    const float* x   = (const float*)d_in[0];
    const int*   ei  = (const int*)d_in[1];
    const float* W1  = (const float*)d_in[3];
    const float* b1  = (const float*)d_in[4];
    const float* W2  = (const float*)d_in[5];
    const float* b2  = (const float*)d_in[6];
    const float* W3  = (const float*)d_in[7];
    const float* b3  = (const float*)d_in[8];
    const float* Wm1 = (const float*)d_in[9];
    const float* bm1 = (const float*)d_in[10];
    const float* Wm2 = (const float*)d_in[11];
    const float* bm2 = (const float*)d_in[12];
    float* out = (float*)d_out;

    const int N = in_sizes[0] / 3;  // 65536
    const int E = in_sizes[1] / 2;  // 524288
    const int* row = ei;
    const int* col = ei + E;

    char* ws = (char*)d_ws;
    size_t off = 0;
    auto alloc = [&](size_t bytes) {
        void* p = ws + off;
        off += (bytes + 255) & ~(size_t)255;
        return p;
    };
    int*   cnt      = (int*)alloc((size_t)N * 4);
    int*   rowptr   = (int*)alloc((size_t)N * 4);
    float* dinv     = (float*)alloc((size_t)N * 4);
    int*   bsum     = (int*)alloc(256 * 4);
    int*   rank     = (int*)alloc((size_t)E * 4);
    int2*  adj      = (int2*)alloc((size_t)E * 8);
    bf16*  h1       = (bf16*)alloc((size_t)N * 64 * 2);
    bf16*  h2       = (bf16*)alloc((size_t)N * 256 * 2);
    bf16*  agg3     = (bf16*)alloc((size_t)N * 256 * 2);
    bf16*  WT2      = (bf16*)alloc(256 * 64 * 2);
    bf16*  WT3      = (bf16*)alloc(512 * 256 * 2);
    float* partials = (float*)alloc((size_t)512 * 1024 * 4);  // 2 MB
    float* m1       = (float*)alloc(64 * 512 * 4);

    // ---- CSR build (once; reused by all 3 layers) ----
    (void)hipMemsetAsync(cnt, 0, (size_t)N * 4, stream);
    k_count<<<(E + 255) / 256, 256, 0, stream>>>(col, cnt, rank, E);
    k_scan_a<<<256, 256, 0, stream>>>(cnt, bsum, dinv);
    k_scan_c<<<256, 256, 0, stream>>>(cnt, bsum, rowptr);
    k_scatter<<<(E + 255) / 256, 256, 0, stream>>>(row, col, dinv, rowptr, rank, adj, E);

    // ---- weight prep (single launch) ----
    k_prep_all<<<(64 * 256 + 256 * 512 + 255) / 256, 256, 0, stream>>>(W2, WT2, W3, WT3);

    // ---- layer 1: fused gather(F=3) + 3->64 GEMM + bias + relu (4-way edge-split) ----
    k_gcn1<<<N / 64, 256, 0, stream>>>(adj, rowptr, cnt, dinv, x, W1, b1, h1, N);

    // ---- layer 2: FUSED gather(F=64) + 64->256 MFMA GEMM + bias + relu ----
    k_gcn2<<<N / 64, 512, 0, stream>>>(adj, rowptr, cnt, dinv, h1, WT2, b2, h2, N);

    // ---- layer 3: gather h2 (F=256), then 256x256-tile MFMA GEMM + pool partials ----
    k_gather_pre<256><<<(N * 64) / 256, 256, 0, stream>>>(adj, rowptr, cnt, dinv, h2, agg3, N);
    k_gemm_pool<<<(N / 256) * 2, 512, 0, stream>>>(agg3, WT3, b3, partials, N, 512, 256);

    // ---- MLP head (pool-final fused into mlp1; 512-block grid) ----
    k_mlp1<<<dim3(64, 8), 256, 0, stream>>>(partials, Wm1, bm1, m1);
    k_mlp2<<<64, 512, 0, stream>>>(m1, Wm2, bm2, out);
}

// Round 12
// 241.245 us; speedup vs baseline: 1.1679x; 1.0057x over previous
//
#include <hip/hip_runtime.h>
#include <hip/hip_bf16.h>

typedef __hip_bfloat16 bf16;
typedef short bf16x8 __attribute__((ext_vector_type(8)));
typedef float f32x4 __attribute__((ext_vector_type(4)));
typedef unsigned int u32x4 __attribute__((ext_vector_type(4)));

// ---------- helpers ----------
__device__ __forceinline__ float b2f_us(unsigned short u) {
    union { unsigned int i; float f; } c;
    c.i = ((unsigned int)u) << 16;
    return c.f;
}
__device__ __forceinline__ unsigned short f2b_us(float f) {
    bf16 h = __float2bfloat16(f);
    return *reinterpret_cast<unsigned short*>(&h);
}
__device__ __forceinline__ void unpack8(uint4 p, float* f) {
    f[0] = b2f_us(p.x & 0xffff); f[1] = b2f_us(p.x >> 16);
    f[2] = b2f_us(p.y & 0xffff); f[3] = b2f_us(p.y >> 16);
    f[4] = b2f_us(p.z & 0xffff); f[5] = b2f_us(p.z >> 16);
    f[6] = b2f_us(p.w & 0xffff); f[7] = b2f_us(p.w >> 16);
}

// async 16B global -> LDS (global_load_lds_dwordx4)
__device__ __forceinline__ void async_copy16(const bf16* g, bf16* l) {
    __builtin_amdgcn_global_load_lds(
        (const __attribute__((address_space(1))) unsigned int*)g,
        (__attribute__((address_space(3))) unsigned int*)l, 16, 0, 0);
}

// ---------- CSR build ----------
// rank trick: atomicAdd's return value IS the within-bucket rank -> scatter needs no atomics.
// Weight prep merged in: prep blocks ride the count launch's tail (independent work,
// one fewer dispatch).
__global__ __launch_bounds__(256) void k_count_prep(const int* __restrict__ col,
                                                    int* __restrict__ cnt,
                                                    int* __restrict__ rank, int E,
                                                    const float* __restrict__ W2,
                                                    bf16* __restrict__ WT2,
                                                    const float* __restrict__ W3,
                                                    bf16* __restrict__ WT3) {
    int cb = (E + 255) >> 8;
    int b = blockIdx.x;
    int t = threadIdx.x;
    if (b < cb) {
        int e = b * 256 + t;
        if (e < E) rank[e] = atomicAdd(cnt + col[e], 1);
    } else {
        int idx = (b - cb) * 256 + t;
        if (idx < 64 * 256) {
            int k = idx >> 8, n = idx & 255;           // K=64, N=256
            WT2[n * 64 + k] = __float2bfloat16(W2[idx]);
        } else {
            int i = idx - 64 * 256;
            if (i < 256 * 512) {
                int k = i >> 9, n = i & 511;           // K=256, N=512
                WT3[(size_t)n * 256 + k] = __float2bfloat16(W3[i]);
            }
        }
    }
}
__global__ __launch_bounds__(256) void k_scan_a(const int* __restrict__ cnt,
                                                int* __restrict__ bsum,
                                                float* __restrict__ dinv) {
    __shared__ int s[256];
    int t = threadIdx.x;
    int i = blockIdx.x * 256 + t;
    int c = cnt[i];
    dinv[i] = rsqrtf((float)c + 1.0f);  // +1 self-loop
    s[t] = c;
    __syncthreads();
#pragma unroll
    for (int off = 128; off >= 1; off >>= 1) {
        if (t < off) s[t] += s[t + off];
        __syncthreads();
    }
    if (t == 0) bsum[blockIdx.x] = s[0];
}
// scan_b merged in: every block redundantly scans the 256 block sums
__global__ __launch_bounds__(256) void k_scan_c(const int* __restrict__ cnt,
                                                const int* __restrict__ bsum,
                                                int* __restrict__ rowptr) {
    __shared__ int s[256];
    __shared__ int sb[256];
    int t = threadIdx.x;
    sb[t] = bsum[t];
    __syncthreads();
#pragma unroll
    for (int off = 1; off < 256; off <<= 1) {
        int v = (t >= off) ? sb[t - off] : 0;
        __syncthreads();
        sb[t] += v;
        __syncthreads();
    }
    int boff = (blockIdx.x > 0) ? sb[blockIdx.x - 1] : 0;
    int base = blockIdx.x * 256;
    int self = cnt[base + t];
    s[t] = self;
    __syncthreads();
#pragma unroll
    for (int off = 1; off < 256; off <<= 1) {
        int v = (t >= off) ? s[t - off] : 0;
        __syncthreads();
        s[t] += v;
        __syncthreads();
    }
    rowptr[base + t] = boff + s[t] - self;  // exclusive
}

__global__ __launch_bounds__(256) void k_scatter(const int* __restrict__ row,
                                                 const int* __restrict__ col,
                                                 const float* __restrict__ dinv,
                                                 const int* __restrict__ rowptr,
                                                 const int* __restrict__ rank,
                                                 int2* __restrict__ adj, int E) {
    int e = blockIdx.x * 256 + threadIdx.x;
    if (e >= E) return;
    int r = row[e], c = col[e];
    int pos = rowptr[c] + rank[e];
    adj[pos] = make_int2(r, __float_as_int(dinv[r]));
}

// ---------- FUSED layer 1: gather x (F=3) + 3->64 GEMM + bias + relu -> h1 ----------
// 4-way edge-split (R7 win: x is L2-resident -> latency regime; 1024 blocks, 4x chains)
__global__ __launch_bounds__(256) void k_gcn1(const int2* __restrict__ adj,
                                              const int* __restrict__ rowptr,
                                              const int* __restrict__ cnt,
                                              const float* __restrict__ dinv,
                                              const float* __restrict__ x,
                                              const float* __restrict__ W,
                                              const float* __restrict__ bias,
                                              bf16* __restrict__ h1, int N) {
    __shared__ float w[256];
    int t = threadIdx.x;
    if (t < 192) w[t] = W[t];
    else w[t] = bias[t - 192];
    __syncthreads();
    int node = blockIdx.x * 64 + (t >> 2);
    int q = t & 3;
    if (node >= N) return;
    float d = dinv[node];
    float a0 = 0.f, a1 = 0.f, a2 = 0.f;
    if (q == 0) {
        float d2 = d * d;
        a0 = x[node * 3] * d2;
        a1 = x[node * 3 + 1] * d2;
        a2 = x[node * 3 + 2] * d2;
    }
    int beg = rowptr[node], deg = cnt[node];
    int e   = beg + (deg * q) / 4;
    int end = beg + (deg * (q + 1)) / 4;
    for (; e + 3 < end; e += 4) {
        int2 ad[4];
#pragma unroll
        for (int u = 0; u < 4; ++u) ad[u] = adj[e + u];
        float xv[4][3];
#pragma unroll
        for (int u = 0; u < 4; ++u) {
            xv[u][0] = x[ad[u].x * 3];
            xv[u][1] = x[ad[u].x * 3 + 1];
            xv[u][2] = x[ad[u].x * 3 + 2];
        }
#pragma unroll
        for (int u = 0; u < 4; ++u) {
            float wt = __int_as_float(ad[u].y) * d;
            a0 += xv[u][0] * wt;
            a1 += xv[u][1] * wt;
            a2 += xv[u][2] * wt;
        }
    }
    for (; e < end; ++e) {
        int2 ad = adj[e];
        float wt = __int_as_float(ad.y) * d;
        a0 += x[ad.x * 3] * wt;
        a1 += x[ad.x * 3 + 1] * wt;
        a2 += x[ad.x * 3 + 2] * wt;
    }
    a0 += __shfl_xor(a0, 1); a1 += __shfl_xor(a1, 1); a2 += __shfl_xor(a2, 1);
    a0 += __shfl_xor(a0, 2); a1 += __shfl_xor(a1, 2); a2 += __shfl_xor(a2, 2);
    bf16* dst = h1 + (size_t)node * 64;
#pragma unroll
    for (int i = 0; i < 2; ++i) {
        int fb = q + 4 * i;
        uint4 r;
        unsigned v[4];
#pragma unroll
        for (int p = 0; p < 4; ++p) {
            int f0 = fb * 8 + p * 2;
            float u0 = fmaxf(a0 * w[f0] + a1 * w[64 + f0] + a2 * w[128 + f0] + w[192 + f0], 0.f);
            int f1 = f0 + 1;
            float u1 = fmaxf(a0 * w[f1] + a1 * w[64 + f1] + a2 * w[128 + f1] + w[192 + f1], 0.f);
            v[p] = (unsigned)f2b_us(u0) | ((unsigned)f2b_us(u1) << 16);
        }
        r.x = v[0]; r.y = v[1]; r.z = v[2]; r.w = v[3];
        *reinterpret_cast<uint4*>(dst + fb * 8) = r;
    }
}

// ========== FUSED layer 2: gather h1 (F=64) + 64->256 MFMA GEMM + bias + relu -> h2 ==========
// (R8 win: short GEMM phase -> no gather-density dilution; B panel LDS-staged once.)
__global__ __launch_bounds__(512, 4) void k_gcn2(const int2* __restrict__ adj,
                                                 const int* __restrict__ rowptr,
                                                 const int* __restrict__ cnt,
                                                 const float* __restrict__ dinv,
                                                 const bf16* __restrict__ h1,
                                                 const bf16* __restrict__ WT2,  // [256][64]
                                                 const float* __restrict__ bias,
                                                 bf16* __restrict__ h2, int N) {
    __shared__ bf16 As[64 * 64];    // 8 KB, XOR-swizzled 16B chunks
    __shared__ bf16 Bs[256 * 64];   // 32 KB, XOR-swizzled
    const int t = threadIdx.x;
    const int m0 = blockIdx.x * 64;
#pragma unroll
    for (int i = 0; i < 4; ++i) {
        int c = i * 512 + t;
        int n = c >> 3, q = c & 7;
        int qs = q ^ (n & 7);
        async_copy16(WT2 + n * 64 + qs * 8, Bs + c * 8);
    }
    {
        const int gi = t >> 4, gl = t & 15;
        const int fs = gl & 7, half = gl >> 3;
        const int fbase = fs * 8;
#pragma unroll 1
        for (int p = 0; p < 2; ++p) {
            int r = p * 32 + gi;
            int node = m0 + r;
            float d = dinv[node];
            float a[8] = {0.f, 0.f, 0.f, 0.f, 0.f, 0.f, 0.f, 0.f};
            if (half == 0) {
                uint4 sp = *reinterpret_cast<const uint4*>(h1 + (size_t)node * 64 + fbase);
                unpack8(sp, a);
                float d2 = d * d;
#pragma unroll
                for (int i = 0; i < 8; i++) a[i] *= d2;
            }
            int beg = rowptr[node], deg = cnt[node];
            int mid = beg + ((deg + 1) >> 1);
            int e = half ? mid : beg;
            int end = half ? (beg + deg) : mid;
            for (; e + 3 < end; e += 4) {
                int2 ad[4];
                uint4 pl[4];
#pragma unroll
                for (int u = 0; u < 4; ++u) ad[u] = adj[e + u];
#pragma unroll
                for (int u = 0; u < 4; ++u)
                    pl[u] = *reinterpret_cast<const uint4*>(h1 + (size_t)ad[u].x * 64 + fbase);
#pragma unroll
                for (int u = 0; u < 4; ++u) {
                    float wt = __int_as_float(ad[u].y) * d;
                    float f[8];
                    unpack8(pl[u], f);
#pragma unroll
                    for (int i = 0; i < 8; i++) a[i] += f[i] * wt;
                }
            }
            for (; e < end; ++e) {
                int2 ad = adj[e];
                float wt = __int_as_float(ad.y) * d;
                uint4 pl = *reinterpret_cast<const uint4*>(h1 + (size_t)ad.x * 64 + fbase);
                float f[8];
                unpack8(pl, f);
#pragma unroll
                for (int i = 0; i < 8; i++) a[i] += f[i] * wt;
            }
#pragma unroll
            for (int i = 0; i < 8; i++) a[i] += __shfl_xor(a[i], 8);
            if (half == 0) {
                u32x4 rr;
                rr.x = (unsigned)f2b_us(a[0]) | ((unsigned)f2b_us(a[1]) << 16);
                rr.y = (unsigned)f2b_us(a[2]) | ((unsigned)f2b_us(a[3]) << 16);
                rr.z = (unsigned)f2b_us(a[4]) | ((unsigned)f2b_us(a[5]) << 16);
                rr.w = (unsigned)f2b_us(a[6]) | ((unsigned)f2b_us(a[7]) << 16);
                int q = fs ^ (r & 7);
                *reinterpret_cast<u32x4*>(&As[r * 64 + q * 8]) = rr;
            }
        }
    }
    __syncthreads();  // drains Bs staging + As writes
    const int w = t >> 6, lane = t & 63;
    const int quad = lane >> 4, l16 = lane & 15;
    const int wmq = w & 3, wnh = w >> 2;
    f32x4 acc[8] = {};
#pragma unroll
    for (int kb = 0; kb < 2; ++kb) {
        int R = wmq * 16 + l16;
        int kc = kb * 4 + quad;
        bf16x8 af = *reinterpret_cast<const bf16x8*>(&As[R * 64 + (kc ^ (R & 7)) * 8]);
#pragma unroll
        for (int j = 0; j < 8; ++j) {
            int n = wnh * 128 + j * 16 + l16;
            bf16x8 bfr = *reinterpret_cast<const bf16x8*>(&Bs[n * 64 + (kc ^ (n & 7)) * 8]);
            acc[j] = __builtin_amdgcn_mfma_f32_16x16x32_bf16(af, bfr, acc[j], 0, 0, 0);
        }
    }
#pragma unroll
    for (int j = 0; j < 8; ++j) {
        int cn = wnh * 128 + j * 16 + l16;
        float bv = bias[cn];
#pragma unroll
        for (int r = 0; r < 4; ++r) {
            int row = m0 + wmq * 16 + quad * 4 + r;
            h2[(size_t)row * 256 + cn] = __float2bfloat16(fmaxf(acc[j][r] + bv, 0.f));
        }
    }
}

// ---------- CSR gather (bf16 -> bf16, incl. self; 8 feats/lane) ----------
// EDGE-SPLIT x2. MUST stay standalone & dense for layer 3 (R3 dilution lesson);
// pattern ceiling ~3.7 TB/s regardless of occupancy (R0 vs R2); FETCH at the
// compulsory per-XCD-L2-miss floor (~137MB vs ~169MB theoretical unique-row bound).
template <int F>
__global__ __launch_bounds__(256, 8) void k_gather_pre(const int2* __restrict__ adj,
                                                       const int* __restrict__ rowptr,
                                                       const int* __restrict__ cnt,
                                                       const float* __restrict__ dinv,
                                                       const bf16* __restrict__ h,
                                                       bf16* __restrict__ agg, int N) {
    constexpr int LPN = F / 8;
    constexpr int GRP = 2 * LPN;
    constexpr int NPB = 256 / GRP;
    int t = threadIdx.x;
    int node = blockIdx.x * NPB + t / GRP;
    if (node >= N) return;
    int gl = t % GRP;
    int fs = gl % LPN;
    int half = gl / LPN;
    int fbase = fs * 8;
    float d = dinv[node];
    size_t sbase = (size_t)node * F + fbase;
    float a[8] = {0.f, 0.f, 0.f, 0.f, 0.f, 0.f, 0.f, 0.f};
    if (half == 0) {
        uint4 sp = *reinterpret_cast<const uint4*>(h + sbase);
        unpack8(sp, a);
        float d2 = d * d;
#pragma unroll
        for (int i = 0; i < 8; i++) a[i] *= d2;
    }
    int beg = rowptr[node];
    int deg = cnt[node];
    int mid = beg + ((deg + 1) >> 1);
    int e   = half ? mid : beg;
    int end = half ? (beg + deg) : mid;
    for (; e + 3 < end; e += 4) {
        int2 ad[4];
        uint4 p[4];
#pragma unroll
        for (int u = 0; u < 4; ++u) ad[u] = adj[e + u];
#pragma unroll
        for (int u = 0; u < 4; ++u)
            p[u] = *reinterpret_cast<const uint4*>(h + (size_t)ad[u].x * F + fbase);
#pragma unroll
        for (int u = 0; u < 4; ++u) {
            float wt = __int_as_float(ad[u].y) * d;
            float f[8];
            unpack8(p[u], f);
#pragma unroll
            for (int i = 0; i < 8; i++) a[i] += f[i] * wt;
        }
    }
    for (; e < end; ++e) {
        int2 ad = adj[e];
        float wt = __int_as_float(ad.y) * d;
        uint4 p = *reinterpret_cast<const uint4*>(h + (size_t)ad.x * F + fbase);
        float f[8];
        unpack8(p, f);
#pragma unroll
        for (int i = 0; i < 8; i++) a[i] += f[i] * wt;
    }
#pragma unroll
    for (int i = 0; i < 8; i++) a[i] += __shfl_xor(a[i], LPN);
    if (half == 0) {
        u32x4 r;
        r.x = (unsigned)f2b_us(a[0]) | ((unsigned)f2b_us(a[1]) << 16);
        r.y = (unsigned)f2b_us(a[2]) | ((unsigned)f2b_us(a[3]) << 16);
        r.z = (unsigned)f2b_us(a[4]) | ((unsigned)f2b_us(a[5]) << 16);
        r.w = (unsigned)f2b_us(a[6]) | ((unsigned)f2b_us(a[7]) << 16);
        __builtin_nontemporal_store(r, reinterpret_cast<u32x4*>(agg + sbase));
    }
}

// ---------- MFMA GEMM + bias + relu + per-block pool partials ----------
// 256x256 tile (8 waves, 2x4), BK=32 (R9/R11: faster than 128x128 - halves staged
// bytes, doubles MFMA-per-barrier, keeps proven fragment pattern).
// partials layout: [mt*2+wm][ sum(512) | max(512) ]; block(nt) writes cols nt*256..
__global__ __launch_bounds__(512) void k_gemm_pool(const bf16* __restrict__ A,
                                                   const bf16* __restrict__ BT,
                                                   const float* __restrict__ bias,
                                                   float* __restrict__ partials,
                                                   int M, int N, int K) {
    __shared__ bf16 As[256 * 32];  // 16 KB
    __shared__ bf16 Bs[256 * 32];  // 16 KB
    const int t = threadIdx.x;
    const int wave = t >> 6, lane = t & 63;
    const int quad = lane >> 4, l16 = lane & 15;
    const int wm = wave & 1, wn = wave >> 1;   // wm: m-half(128), wn: n-quarter(64)
    const int mt = blockIdx.x >> 1, nt = blockIdx.x & 1;
    const int m0 = mt * 256, n0 = nt * 256;

    f32x4 acc[8][4] = {};
    for (int kb = 0; kb < K; kb += 32) {
#pragma unroll
        for (int rnd = 0; rnd < 2; ++rnd) {
            int c = rnd * 512 + t;         // chunk 0..1023; 16B each; wave-linear
            int r = c >> 2, seg = c & 3;
            async_copy16(A + (size_t)(m0 + r) * K + kb + seg * 8, As + c * 8);
            async_copy16(BT + (size_t)(n0 + r) * K + kb + seg * 8, Bs + c * 8);
        }
        __syncthreads();
        bf16x8 af[8], bfr[4];
#pragma unroll
        for (int i = 0; i < 8; i++)
            af[i] = *reinterpret_cast<const bf16x8*>(&As[(wm * 128 + i * 16 + l16) * 32 + quad * 8]);
#pragma unroll
        for (int j = 0; j < 4; j++)
            bfr[j] = *reinterpret_cast<const bf16x8*>(&Bs[(wn * 64 + j * 16 + l16) * 32 + quad * 8]);
#pragma unroll
        for (int i = 0; i < 8; i++)
#pragma unroll
            for (int j = 0; j < 4; j++)
                acc[i][j] = __builtin_amdgcn_mfma_f32_16x16x32_bf16(af[i], bfr[j], acc[i][j], 0, 0, 0);
        __syncthreads();
    }
    size_t pbase = (size_t)(mt * 2 + wm) * 1024;
#pragma unroll
    for (int j = 0; j < 4; j++) {
        int f = wn * 64 + j * 16 + l16;      // within 256-col block
        float bv = bias[n0 + f];
        float s = 0.f, mx = 0.f;
#pragma unroll
        for (int i = 0; i < 8; i++)
#pragma unroll
            for (int r = 0; r < 4; r++) {
                float v = fmaxf(acc[i][j][r] + bv, 0.f);
                s += v;
                mx = fmaxf(mx, v);
            }
        s += __shfl_xor(s, 16);
        s += __shfl_xor(s, 32);
        mx = fmaxf(mx, __shfl_xor(mx, 16));
        mx = fmaxf(mx, __shfl_xor(mx, 32));
        if (quad == 0) {
            partials[pbase + n0 + f] = s;
            partials[pbase + 512 + n0 + f] = mx;
        }
    }
}

// ---------- MLP layer 1 + pool-final (PROVEN R8 shape: 512 blocks, high occupancy).
// R9 lesson: single-block-per-graph fused MLP = 2.7% occupancy, 70us. Keep 64x8 grid.
__global__ __launch_bounds__(256) void k_mlp1(const float* __restrict__ partials,
                                              const float* __restrict__ Wm1,
                                              const float* __restrict__ bm1,
                                              float* __restrict__ o) {
    __shared__ float hg[1024];
    __shared__ float red[256];
    int g = blockIdx.x;
    int t = threadIdx.x;
    // pool: graph g spans (mt*2+wm) indices g*8..g*8+8; layout [k][sum512|max512]
    for (int ff = t; ff < 512; ff += 256) {
        float S = 0.f, M = 0.f;
#pragma unroll
        for (int k = 0; k < 8; ++k) {
            size_t pbase = (size_t)(g * 8 + k) * 1024;
            S += partials[pbase + ff];
            M = fmaxf(M, partials[pbase + 512 + ff]);
        }
        hg[ff] = S * (1.0f / 1024.0f);
        hg[512 + ff] = M;
    }
    __syncthreads();
    int f64 = t & 63, kq = t >> 6;
    int f = blockIdx.y * 64 + f64;
    float acc = 0.f;
    int k0 = kq * 256;
#pragma unroll 8
    for (int k = k0; k < k0 + 256; ++k)
        acc += hg[k] * Wm1[(size_t)k * 512 + f];
    red[t] = acc;
    __syncthreads();
    if (t < 64) {
        float total = red[t] + red[t + 64] + red[t + 128] + red[t + 192] + bm1[f];
        o[g * 512 + f] = fmaxf(total, 0.f);
    }
}

__global__ __launch_bounds__(512) void k_mlp2(const float* __restrict__ h,
                                              const float* __restrict__ Wm2,
                                              const float* __restrict__ bm2,
                                              float* __restrict__ out) {
    int g = blockIdx.x;
    int t = threadIdx.x;
    int j = t >> 5, lane32 = t & 31;
    float acc = 0.f;
    if (j < 10) {
        int k0 = lane32 * 16;
#pragma unroll
        for (int i = 0; i < 16; ++i)
            acc += h[g * 512 + k0 + i] * Wm2[(size_t)(k0 + i) * 10 + j];
    }
#pragma unroll
    for (int m = 16; m >= 1; m >>= 1) acc += __shfl_xor(acc, m);
    if (j < 10 && lane32 == 0) out[g * 10 + j] = acc + bm2[j];
}

extern "C" void kernel_launch(void* const* d_in, const int* in_sizes, int n_in,
                              void* d_out, int out_size, void* d_ws, size_t ws_size,
                              hipStream_t stream) {
    const float* x   = (const float*)d_in[0];
    const int*   ei  = (const int*)d_in[1];
    const float* W1  = (const float*)d_in[3];
    const float* b1  = (const float*)d_in[4];
    const float* W2  = (const float*)d_in[5];
    const float* b2  = (const float*)d_in[6];
    const float* W3  = (const float*)d_in[7];
    const float* b3  = (const float*)d_in[8];
    const float* Wm1 = (const float*)d_in[9];
    const float* bm1 = (const float*)d_in[10];
    const float* Wm2 = (const float*)d_in[11];
    const float* bm2 = (const float*)d_in[12];
    float* out = (float*)d_out;

    const int N = in_sizes[0] / 3;  // 65536
    const int E = in_sizes[1] / 2;  // 524288
    const int* row = ei;
    const int* col = ei + E;

    char* ws = (char*)d_ws;
    size_t off = 0;
    auto alloc = [&](size_t bytes) {
        void* p = ws + off;
        off += (bytes + 255) & ~(size_t)255;
        return p;
    };
    int*   cnt      = (int*)alloc((size_t)N * 4);
    int*   rowptr   = (int*)alloc((size_t)N * 4);
    float* dinv     = (float*)alloc((size_t)N * 4);
    int*   bsum     = (int*)alloc(256 * 4);
    int*   rank     = (int*)alloc((size_t)E * 4);
    int2*  adj      = (int2*)alloc((size_t)E * 8);
    bf16*  h1       = (bf16*)alloc((size_t)N * 64 * 2);
    bf16*  h2       = (bf16*)alloc((size_t)N * 256 * 2);
    bf16*  agg3     = (bf16*)alloc((size_t)N * 256 * 2);
    bf16*  WT2      = (bf16*)alloc(256 * 64 * 2);
    bf16*  WT3      = (bf16*)alloc(512 * 256 * 2);
    float* partials = (float*)alloc((size_t)512 * 1024 * 4);  // 2 MB
    float* m1       = (float*)alloc(64 * 512 * 4);

    // ---- CSR build (once; reused by all 3 layers); weight prep rides the count launch ----
    (void)hipMemsetAsync(cnt, 0, (size_t)N * 4, stream);
    const int cb = (E + 255) / 256;
    const int pb = (64 * 256 + 256 * 512 + 255) / 256;
    k_count_prep<<<cb + pb, 256, 0, stream>>>(col, cnt, rank, E, W2, WT2, W3, WT3);
    k_scan_a<<<256, 256, 0, stream>>>(cnt, bsum, dinv);
    k_scan_c<<<256, 256, 0, stream>>>(cnt, bsum, rowptr);
    k_scatter<<<(E + 255) / 256, 256, 0, stream>>>(row, col, dinv, rowptr, rank, adj, E);

    // ---- layer 1: fused gather(F=3) + 3->64 GEMM + bias + relu (4-way edge-split) ----
    k_gcn1<<<N / 64, 256, 0, stream>>>(adj, rowptr, cnt, dinv, x, W1, b1, h1, N);

    // ---- layer 2: FUSED gather(F=64) + 64->256 MFMA GEMM + bias + relu ----
    k_gcn2<<<N / 64, 512, 0, stream>>>(adj, rowptr, cnt, dinv, h1, WT2, b2, h2, N);

    // ---- layer 3: gather h2 (F=256), then 256x256-tile MFMA GEMM + pool partials ----
    k_gather_pre<256><<<(N * 64) / 256, 256, 0, stream>>>(adj, rowptr, cnt, dinv, h2, agg3, N);
    k_gemm_pool<<<(N / 256) * 2, 512, 0, stream>>>(agg3, WT3, b3, partials, N, 512, 256);

    // ---- MLP head (pool-final fused into mlp1; 512-block grid) ----
    k_mlp1<<<dim3(64, 8), 256, 0, stream>>>(partials, Wm1, bm1, m1);
    k_mlp2<<<64, 512, 0, stream>>>(m1, Wm2, bm2, out);
}